// Round 12
// baseline (1220.152 us; speedup 1.0000x reference)
//
#include <hip/hip_runtime.h>

// ---------------------------------------------------------------------------
// RingLlamaAttention on MI355X (gfx950)
// batched cast f32->bf16 | rope tables | Q gemm (128^2) + K,vT gemms (256^2
// pipelined) | rope apply (vectorized) | flash attention (32x32 MFMA,
// QBLK=128, KVBLK=32 dbuf, per-lane defer-max, exp2 softmax, deferred
// l-reduce, setprio) | O gemm (128^2) -> f32 out
// Shapes: B=2, S=4096, s_local=1024, H=4096, nh=32, hd=128, K=4096
// ---------------------------------------------------------------------------

using bf16x8 = __attribute__((ext_vector_type(8))) short;
using f32x4  = __attribute__((ext_vector_type(4))) float;
using f32x16 = __attribute__((ext_vector_type(16))) float;

__device__ inline unsigned short f32_to_bf16_bits(float f) {
  unsigned int u = __float_as_uint(f);
  u += 0x7FFFu + ((u >> 16) & 1u);   // round-to-nearest-even
  return (unsigned short)(u >> 16);
}
__device__ inline float bf16_bits_to_f32(unsigned short h) {
  return __uint_as_float(((unsigned int)h) << 16);
}

// async global->LDS, 16B per lane (dest must be wave-uniform base + lane*16)
__device__ __forceinline__ void load_lds16(const unsigned short* g, unsigned short* l) {
  __builtin_amdgcn_global_load_lds(
      (const __attribute__((address_space(1))) void*)g,
      (__attribute__((address_space(3))) void*)l, 16, 0, 0);
}

// ---- batched f32 -> bf16 cast: one launch for hs + 4 weight matrices ----
__global__ void cast_f32_bf16_batched(const float* __restrict__ hs,
                                      const float* __restrict__ w0,
                                      const float* __restrict__ w1,
                                      const float* __restrict__ w2,
                                      const float* __restrict__ w3,
                                      unsigned short* __restrict__ out) {
  const long hs4 = 2L * 4096 * 4096 / 4;
  const long w4  = 4096L * 4096 / 4;
  long i = (long)blockIdx.x * blockDim.x + threadIdx.x;
  long stride = (long)gridDim.x * blockDim.x;
  const long total = hs4 + 4 * w4;
  for (; i < total; i += stride) {
    const float* src;
    long j = i;
    if (j < hs4) { src = hs; }
    else {
      j -= hs4;
      long wi = j / w4;
      j -= wi * w4;
      src = (wi == 0) ? w0 : (wi == 1) ? w1 : (wi == 2) ? w2 : w3;
    }
    float4 v = reinterpret_cast<const float4*>(src)[j];
    ushort4 o;
    o.x = f32_to_bf16_bits(v.x);
    o.y = f32_to_bf16_bits(v.y);
    o.z = f32_to_bf16_bits(v.z);
    o.w = f32_to_bf16_bits(v.w);
    reinterpret_cast<ushort4*>(out)[i] = o;
  }
}

// ---- RoPE cos/sin tables ----
__global__ void rope_tables(float* __restrict__ cos_t, float* __restrict__ sin_t) {
  int idx = blockIdx.x * 256 + threadIdx.x;
  if (idx >= 4096 * 64) return;
  int p = idx >> 6, i = idx & 63;
  float inv = __expf(-(float)i * (9.210340371976184f / 64.0f));  // theta^(-i/64)
  float f = (float)p * inv;
  cos_t[idx] = cosf(f);
  sin_t[idx] = sinf(f);
}

// ---- RoPE apply, vectorized: thread = (tok, head, 8-freq chunk) ----
__global__ void rope_apply_v(unsigned short* __restrict__ buf,
                             const float4* __restrict__ cos4,
                             const float4* __restrict__ sin4,
                             long nchunks, int pos_mask, float gain) {
  long idx = (long)blockIdx.x * 256 + threadIdx.x;
  if (idx >= nchunks) return;
  long tok = idx >> 8;
  int rem = (int)(idx & 255);
  int head = rem >> 3, c = rem & 7;
  int pos = (int)(tok & (long)pos_mask);
  float4 ct0 = cos4[pos * 16 + c * 2];
  float4 ct1 = cos4[pos * 16 + c * 2 + 1];
  float4 st0 = sin4[pos * 16 + c * 2];
  float4 st1 = sin4[pos * 16 + c * 2 + 1];
  float cs[8] = {ct0.x, ct0.y, ct0.z, ct0.w, ct1.x, ct1.y, ct1.z, ct1.w};
  float sn[8] = {st0.x, st0.y, st0.z, st0.w, st1.x, st1.y, st1.z, st1.w};
  long base = tok * 4096 + head * 128 + c * 8;
  bf16x8 x1 = *reinterpret_cast<const bf16x8*>(buf + base);
  bf16x8 x2 = *reinterpret_cast<const bf16x8*>(buf + base + 64);
  bf16x8 o1, o2;
#pragma unroll
  for (int j = 0; j < 8; j++) {
    float a = bf16_bits_to_f32((unsigned short)x1[j]);
    float b = bf16_bits_to_f32((unsigned short)x2[j]);
    o1[j] = (short)f32_to_bf16_bits((a * cs[j] - b * sn[j]) * gain);
    o2[j] = (short)f32_to_bf16_bits((b * cs[j] + a * sn[j]) * gain);
  }
  *reinterpret_cast<bf16x8*>(buf + base) = o1;
  *reinterpret_cast<bf16x8*>(buf + base + 64) = o2;
}

__device__ inline void storeC(float* p, float v) { *p = v; }
__device__ inline void storeC(unsigned short* p, float v) { *p = f32_to_bf16_bits(v); }

// ---- 128^2 GEMM (m97 structure): used for the small Q / O projections ----
template <typename OUT_T>
__global__ __launch_bounds__(256) void gemm_bt(const unsigned short* __restrict__ A,
                                               const unsigned short* __restrict__ B,
                                               OUT_T* __restrict__ C,
                                               long Astride_z, long Cstride_z, int N) {
  __shared__ unsigned short As[128 * 32];
  __shared__ unsigned short Bs[128 * 32];
  const int tid = threadIdx.x;
  const int bn = blockIdx.x, bm = blockIdx.y, bz = blockIdx.z;
  const unsigned short* Ab = A + (long)bz * Astride_z + (long)bm * 128 * 4096;
  const unsigned short* Bb = B + (long)bn * 128 * 4096;
  OUT_T* Cb = C + (long)bz * Cstride_z + (long)bm * 128 * N + (long)bn * 128;

  const int lane = tid & 63;
  const int w = tid >> 6;
  const int wr = (w >> 1) * 64, wc = (w & 1) * 64;
  const int fr = lane & 15, fg = lane >> 4;

  f32x4 acc[4][4] = {};

  const int c0 = tid, c1 = tid + 256;
  const int rA0 = c0 >> 2, kc0 = c0 & 3;
  const int rA1 = c1 >> 2, kc1 = c1 & 3;

  for (int k0 = 0; k0 < 4096; k0 += 32) {
    load_lds16(Ab + (long)rA0 * 4096 + k0 + kc0 * 8, As + c0 * 8);
    load_lds16(Ab + (long)rA1 * 4096 + k0 + kc1 * 8, As + c1 * 8);
    load_lds16(Bb + (long)rA0 * 4096 + k0 + kc0 * 8, Bs + c0 * 8);
    load_lds16(Bb + (long)rA1 * 4096 + k0 + kc1 * 8, Bs + c1 * 8);
    __syncthreads();
    bf16x8 af[4], bfv[4];
#pragma unroll
    for (int m = 0; m < 4; m++)
      af[m] = *reinterpret_cast<const bf16x8*>(As + (wr + m * 16 + fr) * 32 + fg * 8);
#pragma unroll
    for (int n = 0; n < 4; n++)
      bfv[n] = *reinterpret_cast<const bf16x8*>(Bs + (wc + n * 16 + fr) * 32 + fg * 8);
#pragma unroll
    for (int m = 0; m < 4; m++)
#pragma unroll
      for (int n = 0; n < 4; n++)
        acc[m][n] = __builtin_amdgcn_mfma_f32_16x16x32_bf16(af[m], bfv[n], acc[m][n], 0, 0, 0);
    __syncthreads();
  }
#pragma unroll
  for (int m = 0; m < 4; m++)
#pragma unroll
    for (int n = 0; n < 4; n++)
#pragma unroll
      for (int r = 0; r < 4; r++) {
        int row = wr + m * 16 + fg * 4 + r;
        int col = wc + n * 16 + fr;
        storeC(Cb + (long)row * N + col, acc[m][n][r]);
      }
}

// ---- 256^2 depth-2 pipelined GEMM (verified R5): C = A[M,K]*B[N,K]^T ----
#define STG2(Gb, Lb, h, kc)                                                    \
  load_lds16((Gb) + (long)((h) * 128 + srow) * 4096 + sslot * 8 + (kc),        \
             (Lb) + tid * 8);                                                  \
  load_lds16((Gb) + (long)((h) * 128 + 64 + srow) * 4096 + sslot * 8 + (kc),   \
             (Lb) + 4096 + tid * 8);

#define MFMAQ(MH, NH)                                                          \
  _Pragma("unroll") for (int mi = 0; mi < 4; ++mi)                             \
    _Pragma("unroll") for (int ni = 0; ni < 2; ++ni)                           \
      _Pragma("unroll") for (int kk = 0; kk < 2; ++kk)                         \
        acc[(MH) * 4 + mi][(NH) * 2 + ni] =                                    \
            __builtin_amdgcn_mfma_f32_16x16x32_bf16(                           \
                a[mi][kk], b[(NH) * 2 + ni][kk],                               \
                acc[(MH) * 4 + mi][(NH) * 2 + ni], 0, 0, 0);

#define TILE(P, KC, MODE)                                                      \
  {                                                                            \
    const unsigned short* Ar = lds + wm * 16384 + (P) * 8192;                  \
    const unsigned short* Br =                                                 \
        lds + 32768 + (wn >> 1) * 16384 + (P) * 8192 + (wn & 1) * 4096;        \
    _Pragma("unroll") for (int mf = 0; mf < 4; ++mf) {                         \
      a[mf][0] = *reinterpret_cast<const bf16x8*>(Ar + mf * 1024 + ao0);       \
      a[mf][1] = *reinterpret_cast<const bf16x8*>(Ar + mf * 1024 + ao1);       \
    }                                                                          \
    _Pragma("unroll") for (int nf = 0; nf < 2; ++nf) {                         \
      b[nf][0] = *reinterpret_cast<const bf16x8*>(Br + nf * 1024 + ao0);       \
      b[nf][1] = *reinterpret_cast<const bf16x8*>(Br + nf * 1024 + ao1);       \
    }                                                                          \
    __builtin_amdgcn_s_setprio(1);                                             \
    MFMAQ(0, 0);                                                               \
    __builtin_amdgcn_s_setprio(0);                                             \
    _Pragma("unroll") for (int nf = 2; nf < 4; ++nf) {                         \
      b[nf][0] = *reinterpret_cast<const bf16x8*>(Br + nf * 1024 + ao0);       \
      b[nf][1] = *reinterpret_cast<const bf16x8*>(Br + nf * 1024 + ao1);       \
    }                                                                          \
    __builtin_amdgcn_s_setprio(1);                                             \
    MFMAQ(0, 1);                                                               \
    __builtin_amdgcn_s_setprio(0);                                             \
    asm volatile("s_waitcnt lgkmcnt(0)" ::: "memory");                         \
    asm volatile("s_barrier" ::: "memory"); /* B[.][P] fully read */           \
    if ((MODE) == 0) {                                                         \
      STG2(Bg, lds + 32768 + (P) * 8192, 0, KC);                               \
      STG2(Bg, lds + 49152 + (P) * 8192, 1, KC);                               \
    }                                                                          \
    _Pragma("unroll") for (int mf = 0; mf < 4; ++mf) {                         \
      a[mf][0] = *reinterpret_cast<const bf16x8*>(Ar + (4 + mf) * 1024 + ao0); \
      a[mf][1] = *reinterpret_cast<const bf16x8*>(Ar + (4 + mf) * 1024 + ao1); \
    }                                                                          \
    __builtin_amdgcn_s_setprio(1);                                             \
    MFMAQ(1, 0);                                                               \
    __builtin_amdgcn_s_setprio(0);                                             \
    asm volatile("s_waitcnt lgkmcnt(0)" ::: "memory");                         \
    asm volatile("s_barrier" ::: "memory"); /* A[.][P] fully read */           \
    if ((MODE) == 0) {                                                         \
      STG2(Ag, lds + (P) * 8192, 0, KC);                                       \
      STG2(Ag, lds + 16384 + (P) * 8192, 1, KC);                               \
    }                                                                          \
    __builtin_amdgcn_s_setprio(1);                                             \
    MFMAQ(1, 1);                                                               \
    __builtin_amdgcn_s_setprio(0);                                             \
    if ((MODE) == 0) asm volatile("s_waitcnt vmcnt(8)" ::: "memory");          \
    if ((MODE) == 1) asm volatile("s_waitcnt vmcnt(0)" ::: "memory");          \
    asm volatile("s_barrier" ::: "memory"); /* next tile's data landed */      \
  }

template <typename OUT_T>
__global__ __launch_bounds__(512, 2) void gemm256(const unsigned short* __restrict__ A,
                                                  const unsigned short* __restrict__ B,
                                                  OUT_T* __restrict__ C,
                                                  long Astride_z, long Cstride_z, int N) {
  __shared__ unsigned short lds[65536];   // 128 KiB
  const int tid = threadIdx.x;
  const int bn = blockIdx.x, bm = blockIdx.y, bz = blockIdx.z;
  const unsigned short* Ag = A + (long)bz * Astride_z + (long)bm * 256 * 4096;
  const unsigned short* Bg = B + (long)bn * 256 * 4096;

  const int w = tid >> 6, lane = tid & 63;
  const int wm = w >> 2, wn = w & 3;
  const int fr = lane & 15, fg = lane >> 4;
  const int ao0 = fr * 64 + ((fg ^ (fr & 7)) * 8);
  const int ao1 = fr * 64 + (((4 + fg) ^ (fr & 7)) * 8);
  const int srow = tid >> 3;
  const int sslot = (tid & 7) ^ (srow & 7);

  f32x4 acc[8][4] = {};
  bf16x8 a[4][2], b[4][2];

  STG2(Ag, lds + 0, 0, 0);     STG2(Ag, lds + 16384, 1, 0);
  STG2(Bg, lds + 32768, 0, 0); STG2(Bg, lds + 49152, 1, 0);
  STG2(Ag, lds + 8192, 0, 64);  STG2(Ag, lds + 24576, 1, 64);
  STG2(Bg, lds + 40960, 0, 64); STG2(Bg, lds + 57344, 1, 64);
  asm volatile("s_waitcnt vmcnt(8)" ::: "memory");
  asm volatile("s_barrier" ::: "memory");

  for (int ti = 0; ti < 31; ++ti) {        // tiles 0..61
    TILE(0, (2 * ti + 2) * 64, 0);
    TILE(1, (2 * ti + 3) * 64, 0);
  }
  TILE(0, 0, 1);
  TILE(1, 0, 2);

  OUT_T* Cb = C + (long)bz * Cstride_z + ((long)bm * 256) * N + bn * 256;
#pragma unroll
  for (int mf = 0; mf < 8; ++mf)
#pragma unroll
    for (int nf = 0; nf < 4; ++nf)
#pragma unroll
      for (int rr = 0; rr < 4; ++rr) {
        int row = wm * 128 + mf * 16 + fg * 4 + rr;
        int col = wn * 64 + nf * 16 + fr;
        storeC(Cb + (long)row * N + col, acc[mf][nf][rr]);
      }
}

// ---- flash attention: 32x32 MFMA, QBLK=128 (4 waves x 32 q), KVBLK=32 ----
// Halves LDS reads per FLOP vs 16x16 (32768 FLOP/b128). grid (8,32,2).
// K staged [32 keys][16 slots] slot^(key&15); vT staged [128 f][4 slots]
// slot^(feat&3); dbuf + R7-verified drain discipline.
// 32x32x16 layouts: A/B: row|col=lane&31, k=(lane>>5)*8+j.
// C/D [m74/m101]: col=lane&31, row=(reg&3)+8*(reg>>2)+4*(lane>>5).
// Ps: [32 rows][40 elems], slot = kc ^ (row>>3 & 3) (conflict-free writes).
#define AT_STAGE(P, kv)                                                        \
  _Pragma("unroll") for (int i = 0; i < 2; i++) {                              \
    int c = tid + 256 * i;                                                     \
    int key = c >> 4, s0 = c & 15;                                             \
    int Lg = s0 ^ (key & 15);                                                  \
    load_lds16(kbase + (long)((kv) + key) * 4096 + Lg * 8, &Ks[P][c * 8]);     \
  }                                                                            \
  _Pragma("unroll") for (int i = 0; i < 2; i++) {                              \
    int c = tid + 256 * i;                                                     \
    int f0 = c >> 2, s0 = c & 3;                                               \
    int Lg = s0 ^ (f0 & 3);                                                    \
    load_lds16(vbase + (long)f0 * 8192 + (kv) + Lg * 8, &Vl[P][c * 8]);        \
  }

__global__ __launch_bounds__(256) void attn_fwd(const unsigned short* __restrict__ qb,
                                                const unsigned short* __restrict__ kb,
                                                const unsigned short* __restrict__ vT,
                                                unsigned short* __restrict__ ob) {
  __shared__ unsigned short Ks[2][32 * 128];   // 8KB x2
  __shared__ unsigned short Vl[2][128 * 32];   // 8KB x2
  __shared__ unsigned short Ps[4][32 * 40];    // 10KB

  const int qt = blockIdx.x, h = blockIdx.y, b = blockIdx.z;
  const int tid = threadIdx.x, w = tid >> 6, lane = tid & 63;
  const int lq = lane & 31;          // q-row / key / d-col within 32
  const int kg = lane >> 5;          // k-group (0/1)

  const unsigned short* kbase = kb + (long)b * 4096 * 4096 + h * 128;
  const unsigned short* vbase = vT + (long)h * 128 * 8192 + (long)b * 4096;

  // Q fragments: qf[t] covers d = 16t + kg*8 + j, row = lq
  bf16x8 qf[8];
  {
    const unsigned short* qptr =
        qb + ((long)b * 1024 + qt * 128 + w * 32 + lq) * 4096 + h * 128 + kg * 8;
#pragma unroll
    for (int t = 0; t < 8; t++) qf[t] = *reinterpret_cast<const bf16x8*>(qptr + 16 * t);
  }

  f32x16 acc[4] = {};                // O: acc[dsub][reg], col = dsub*32+lq
  float m_run[16], l_run[16];
#pragma unroll
  for (int r = 0; r < 16; r++) { m_run[r] = -1e30f; l_run[r] = 0.0f; }

  AT_STAGE(0, 0);
  asm volatile("s_waitcnt vmcnt(0)" ::: "memory");
  asm volatile("s_barrier" ::: "memory");

  for (int t = 0; t < 128; ++t) {
    const int cur = t & 1;
    if (t < 127) { AT_STAGE(cur ^ 1, (t + 1) * 32); }

    // S = Q K^T : one 32q x 32k tile, 8 k-steps over d=128
    f32x16 sacc = {};
    __builtin_amdgcn_s_setprio(1);
#pragma unroll
    for (int ks = 0; ks < 8; ks++) {
      // B-frag: key = lq, d-chunk dc = 2*ks + kg, slot = dc ^ (lq & 15)
      bf16x8 kf = *reinterpret_cast<const bf16x8*>(
          &Ks[cur][lq * 128 + (((2 * ks + kg) ^ (lq & 15)) & 15) * 8]);
      sacc = __builtin_amdgcn_mfma_f32_32x32x16_bf16(qf[ks], kf, sacc, 0, 0, 0);
    }
    __builtin_amdgcn_s_setprio(0);

    // per-lane defer-max (reg r holds row (r&3)+8*(r>>2)+4*kg, col lq)
    int need = 0;
#pragma unroll
    for (int r = 0; r < 16; r++) need |= (sacc[r] > m_run[r] + 11.5f) ? 1 : 0;
    if (__any(need)) {   // rare: full row max reduce (32 lanes per half) + rescale
#pragma unroll
      for (int r = 0; r < 16; r++) {
        float mx = sacc[r];
        mx = fmaxf(mx, __shfl_xor(mx, 1));
        mx = fmaxf(mx, __shfl_xor(mx, 2));
        mx = fmaxf(mx, __shfl_xor(mx, 4));
        mx = fmaxf(mx, __shfl_xor(mx, 8));
        mx = fmaxf(mx, __shfl_xor(mx, 16));
        float mnew = fmaxf(m_run[r], mx);
        float ef = exp2f(m_run[r] - mnew);
        l_run[r] *= ef;
        m_run[r] = mnew;
#pragma unroll
        for (int d = 0; d < 4; d++) acc[d][r] *= ef;
      }
    }
    // P = exp2(S - m), write to Ps (row, key=lq), accumulate l partials
#pragma unroll
    for (int r = 0; r < 16; r++) {
      float pv = exp2f(sacc[r] - m_run[r]);   // <= 2^11.5
      int row = (r & 3) + 8 * (r >> 2) + 4 * kg;
      Ps[w][row * 40 + (((lq >> 3) ^ (r >> 2)) << 3) + (lq & 7)] = f32_to_bf16_bits(pv);
      l_run[r] += pv;
    }

    // O += P V : A = P (row=lq, k=key), B = V (col = d, k = key)
    bf16x8 pa0 = *reinterpret_cast<const bf16x8*>(
        &Ps[w][lq * 40 + ((kg ^ ((lq >> 3) & 3)) << 3)]);
    bf16x8 pa1 = *reinterpret_cast<const bf16x8*>(
        &Ps[w][lq * 40 + (((kg + 2) ^ ((lq >> 3) & 3)) << 3)]);
    __builtin_amdgcn_s_setprio(1);
#pragma unroll
    for (int dsub = 0; dsub < 4; dsub++) {
      bf16x8 v0 = *reinterpret_cast<const bf16x8*>(
          &Vl[cur][(dsub * 32 + lq) * 32 + ((kg ^ (lq & 3)) << 3)]);
      bf16x8 v1 = *reinterpret_cast<const bf16x8*>(
          &Vl[cur][(dsub * 32 + lq) * 32 + (((kg + 2) ^ (lq & 3)) << 3)]);
      acc[dsub] = __builtin_amdgcn_mfma_f32_32x32x16_bf16(pa0, v0, acc[dsub], 0, 0, 0);
      acc[dsub] = __builtin_amdgcn_mfma_f32_32x32x16_bf16(pa1, v1, acc[dsub], 0, 0, 0);
    }
    __builtin_amdgcn_s_setprio(0);

    if (t < 127) {
      asm volatile("s_waitcnt vmcnt(0) lgkmcnt(0)" ::: "memory");
      asm volatile("s_barrier" ::: "memory");
    }
  }

  // final l reduce (32-lane halves), normalize, store
#pragma unroll
  for (int r = 0; r < 16; r++) {
    float l = l_run[r];
    l += __shfl_xor(l, 1);
    l += __shfl_xor(l, 2);
    l += __shfl_xor(l, 4);
    l += __shfl_xor(l, 8);
    l += __shfl_xor(l, 16);
    float inv = 1.0f / l;
    int row = (r & 3) + 8 * (r >> 2) + 4 * kg;
    unsigned short* op =
        ob + ((long)b * 1024 + qt * 128 + w * 32 + row) * 4096 + h * 128 + lq;
#pragma unroll
    for (int dsub = 0; dsub < 4; dsub++)
      op[dsub * 32] = f32_to_bf16_bits(acc[dsub][r] * inv);
  }
}

// ---------------------------------------------------------------------------
extern "C" void kernel_launch(void* const* d_in, const int* in_sizes, int n_in,
                              void* d_out, int out_size, void* d_ws, size_t ws_size,
                              hipStream_t stream) {
  const float* hs = (const float*)d_in[0];
  const float* wq = (const float*)d_in[1];
  const float* wk = (const float*)d_in[2];
  const float* wv = (const float*)d_in[3];
  const float* wo = (const float*)d_in[4];
  float* out = (float*)d_out;

  const long hsN = 2L * 4096 * 4096;
  const long wN  = 4096L * 4096;

  unsigned short* hs_b = (unsigned short*)d_ws;
  unsigned short* wq_b = hs_b + hsN;
  unsigned short* wk_b = wq_b + wN;
  unsigned short* wv_b = wk_b + wN;
  unsigned short* wo_b = wv_b + wN;
  unsigned short* q_b  = wo_b + wN;             // 2048 x 4096
  unsigned short* k_b  = q_b + 2048L * 4096;    // 8192 x 4096 ([tok][feat])
  unsigned short* vT_b = k_b + 8192L * 4096;    // 4096 x 8192 ([feat][tok])
  unsigned short* at_b = vT_b + 8192L * 4096;   // 2048 x 4096
  float* cos_t = (float*)(at_b + 2048L * 4096);
  float* sin_t = cos_t + 4096 * 64;

  cast_f32_bf16_batched<<<dim3(8192), dim3(256), 0, stream>>>(
      hs, wq, wk, wv, wo, hs_b);

  rope_tables<<<dim3(1024), dim3(256), 0, stream>>>(cos_t, sin_t);

  // Q[tok][feat] — 128^2 kernel
  gemm_bt<unsigned short><<<dim3(32, 8, 2), dim3(256), 0, stream>>>(
      hs_b, wq_b, q_b, 4096L * 4096, 1024L * 4096, 4096);
  // K[tok][feat] — 256^2 pipelined
  gemm256<unsigned short><<<dim3(16, 16, 2), dim3(512), 0, stream>>>(
      hs_b, wk_b, k_b, 4096L * 4096, 4096L * 4096, 4096);
  // vT[feat][tok] = Wv * hs^T — 256^2 pipelined
  gemm256<unsigned short><<<dim3(32, 16, 1), dim3(512), 0, stream>>>(
      wv_b, hs_b, vT_b, 0L, 0L, 8192);

  const float qgain = 0.08838834764831845f * 1.4426950408889634f;
  rope_apply_v<<<dim3(2048), dim3(256), 0, stream>>>(
      q_b, (const float4*)cos_t, (const float4*)sin_t, 2048L * 256, 1023, qgain);
  rope_apply_v<<<dim3(8192), dim3(256), 0, stream>>>(
      k_b, (const float4*)cos_t, (const float4*)sin_t, 8192L * 256, 4095, 1.0f);

  attn_fwd<<<dim3(8, 32, 2), dim3(256), 0, stream>>>(q_b, k_b, vT_b, at_b);

  gemm_bt<float><<<dim3(32, 16, 1), dim3(256), 0, stream>>>(
      at_b, wo_b, out, 0L, 0L, 4096);
}

// Round 13
// 1021.674 us; speedup vs baseline: 1.1943x; 1.1943x over previous
//
#include <hip/hip_runtime.h>

// ---------------------------------------------------------------------------
// RingLlamaAttention on MI355X (gfx950)
// batched cast f32->bf16 | rope tables | Q gemm (128^2) + K,vT gemms (256^2
// pipelined) | merged rope apply (vectorized) | flash attention (QBLK=64,
// K+V dbuf via gload_lds, per-lane defer-max, exp2 softmax, deferred
// l-reduce, setprio) | O gemm (128^2) -> f32 out
// Shapes: B=2, S=4096, s_local=1024, H=4096, nh=32, hd=128, K=4096
// ---------------------------------------------------------------------------

using bf16x8 = __attribute__((ext_vector_type(8))) short;
using f32x4  = __attribute__((ext_vector_type(4))) float;

__device__ inline unsigned short f32_to_bf16_bits(float f) {
  unsigned int u = __float_as_uint(f);
  u += 0x7FFFu + ((u >> 16) & 1u);   // round-to-nearest-even
  return (unsigned short)(u >> 16);
}
__device__ inline float bf16_bits_to_f32(unsigned short h) {
  return __uint_as_float(((unsigned int)h) << 16);
}

// async global->LDS, 16B per lane (dest must be wave-uniform base + lane*16)
__device__ __forceinline__ void load_lds16(const unsigned short* g, unsigned short* l) {
  __builtin_amdgcn_global_load_lds(
      (const __attribute__((address_space(1))) void*)g,
      (__attribute__((address_space(3))) void*)l, 16, 0, 0);
}

// ---- batched f32 -> bf16 cast: one launch for hs + 4 weight matrices ----
__global__ void cast_f32_bf16_batched(const float* __restrict__ hs,
                                      const float* __restrict__ w0,
                                      const float* __restrict__ w1,
                                      const float* __restrict__ w2,
                                      const float* __restrict__ w3,
                                      unsigned short* __restrict__ out) {
  const long hs4 = 2L * 4096 * 4096 / 4;
  const long w4  = 4096L * 4096 / 4;
  long i = (long)blockIdx.x * blockDim.x + threadIdx.x;
  long stride = (long)gridDim.x * blockDim.x;
  const long total = hs4 + 4 * w4;
  for (; i < total; i += stride) {
    const float* src;
    long j = i;
    if (j < hs4) { src = hs; }
    else {
      j -= hs4;
      long wi = j / w4;
      j -= wi * w4;
      src = (wi == 0) ? w0 : (wi == 1) ? w1 : (wi == 2) ? w2 : w3;
    }
    float4 v = reinterpret_cast<const float4*>(src)[j];
    ushort4 o;
    o.x = f32_to_bf16_bits(v.x);
    o.y = f32_to_bf16_bits(v.y);
    o.z = f32_to_bf16_bits(v.z);
    o.w = f32_to_bf16_bits(v.w);
    reinterpret_cast<ushort4*>(out)[i] = o;
  }
}

// ---- RoPE cos/sin tables ----
__global__ void rope_tables(float* __restrict__ cos_t, float* __restrict__ sin_t) {
  int idx = blockIdx.x * 256 + threadIdx.x;
  if (idx >= 4096 * 64) return;
  int p = idx >> 6, i = idx & 63;
  float inv = __expf(-(float)i * (9.210340371976184f / 64.0f));  // theta^(-i/64)
  float f = (float)p * inv;
  cos_t[idx] = cosf(f);
  sin_t[idx] = sinf(f);
}

// ---- merged RoPE apply (Q then K regions), vectorized 8-freq chunks ----
__global__ void rope_apply_qk(unsigned short* __restrict__ qbuf,
                              unsigned short* __restrict__ kbuf,
                              const float4* __restrict__ cos4,
                              const float4* __restrict__ sin4,
                              float qgain) {
  const long qch = 2048L * 256;    // q: 2048 toks x 256 chunks
  const long kch = 8192L * 256;    // k: 8192 toks x 256 chunks
  long idx = (long)blockIdx.x * 256 + threadIdx.x;
  if (idx >= qch + kch) return;
  unsigned short* buf;
  int pos_mask; float gain;
  if (idx < qch) { buf = qbuf; pos_mask = 1023; gain = qgain; }
  else { idx -= qch; buf = kbuf; pos_mask = 4095; gain = 1.0f; }
  long tok = idx >> 8;
  int rem = (int)(idx & 255);
  int head = rem >> 3, c = rem & 7;
  int pos = (int)(tok & (long)pos_mask);
  float4 ct0 = cos4[pos * 16 + c * 2];
  float4 ct1 = cos4[pos * 16 + c * 2 + 1];
  float4 st0 = sin4[pos * 16 + c * 2];
  float4 st1 = sin4[pos * 16 + c * 2 + 1];
  float cs[8] = {ct0.x, ct0.y, ct0.z, ct0.w, ct1.x, ct1.y, ct1.z, ct1.w};
  float sn[8] = {st0.x, st0.y, st0.z, st0.w, st1.x, st1.y, st1.z, st1.w};
  long base = tok * 4096 + head * 128 + c * 8;
  bf16x8 x1 = *reinterpret_cast<const bf16x8*>(buf + base);
  bf16x8 x2 = *reinterpret_cast<const bf16x8*>(buf + base + 64);
  bf16x8 o1, o2;
#pragma unroll
  for (int j = 0; j < 8; j++) {
    float a = bf16_bits_to_f32((unsigned short)x1[j]);
    float b = bf16_bits_to_f32((unsigned short)x2[j]);
    o1[j] = (short)f32_to_bf16_bits((a * cs[j] - b * sn[j]) * gain);
    o2[j] = (short)f32_to_bf16_bits((b * cs[j] + a * sn[j]) * gain);
  }
  *reinterpret_cast<bf16x8*>(buf + base) = o1;
  *reinterpret_cast<bf16x8*>(buf + base + 64) = o2;
}

__device__ inline void storeC(float* p, float v) { *p = v; }
__device__ inline void storeC(unsigned short* p, float v) { *p = f32_to_bf16_bits(v); }

// ---- 128^2 GEMM (m97 structure): used for the small Q / O projections ----
template <typename OUT_T>
__global__ __launch_bounds__(256) void gemm_bt(const unsigned short* __restrict__ A,
                                               const unsigned short* __restrict__ B,
                                               OUT_T* __restrict__ C,
                                               long Astride_z, long Cstride_z, int N) {
  __shared__ unsigned short As[128 * 32];
  __shared__ unsigned short Bs[128 * 32];
  const int tid = threadIdx.x;
  const int bn = blockIdx.x, bm = blockIdx.y, bz = blockIdx.z;
  const unsigned short* Ab = A + (long)bz * Astride_z + (long)bm * 128 * 4096;
  const unsigned short* Bb = B + (long)bn * 128 * 4096;
  OUT_T* Cb = C + (long)bz * Cstride_z + (long)bm * 128 * N + (long)bn * 128;

  const int lane = tid & 63;
  const int w = tid >> 6;
  const int wr = (w >> 1) * 64, wc = (w & 1) * 64;
  const int fr = lane & 15, fg = lane >> 4;

  f32x4 acc[4][4] = {};

  const int c0 = tid, c1 = tid + 256;
  const int rA0 = c0 >> 2, kc0 = c0 & 3;
  const int rA1 = c1 >> 2, kc1 = c1 & 3;

  for (int k0 = 0; k0 < 4096; k0 += 32) {
    load_lds16(Ab + (long)rA0 * 4096 + k0 + kc0 * 8, As + c0 * 8);
    load_lds16(Ab + (long)rA1 * 4096 + k0 + kc1 * 8, As + c1 * 8);
    load_lds16(Bb + (long)rA0 * 4096 + k0 + kc0 * 8, Bs + c0 * 8);
    load_lds16(Bb + (long)rA1 * 4096 + k0 + kc1 * 8, Bs + c1 * 8);
    __syncthreads();
    bf16x8 af[4], bfv[4];
#pragma unroll
    for (int m = 0; m < 4; m++)
      af[m] = *reinterpret_cast<const bf16x8*>(As + (wr + m * 16 + fr) * 32 + fg * 8);
#pragma unroll
    for (int n = 0; n < 4; n++)
      bfv[n] = *reinterpret_cast<const bf16x8*>(Bs + (wc + n * 16 + fr) * 32 + fg * 8);
#pragma unroll
    for (int m = 0; m < 4; m++)
#pragma unroll
      for (int n = 0; n < 4; n++)
        acc[m][n] = __builtin_amdgcn_mfma_f32_16x16x32_bf16(af[m], bfv[n], acc[m][n], 0, 0, 0);
    __syncthreads();
  }
#pragma unroll
  for (int m = 0; m < 4; m++)
#pragma unroll
    for (int n = 0; n < 4; n++)
#pragma unroll
      for (int r = 0; r < 4; r++) {
        int row = wr + m * 16 + fg * 4 + r;
        int col = wc + n * 16 + fr;
        storeC(Cb + (long)row * N + col, acc[m][n][r]);
      }
}

// ---- 256^2 depth-2 pipelined GEMM (verified R5): C = A[M,K]*B[N,K]^T ----
#define STG2(Gb, Lb, h, kc)                                                    \
  load_lds16((Gb) + (long)((h) * 128 + srow) * 4096 + sslot * 8 + (kc),        \
             (Lb) + tid * 8);                                                  \
  load_lds16((Gb) + (long)((h) * 128 + 64 + srow) * 4096 + sslot * 8 + (kc),   \
             (Lb) + 4096 + tid * 8);

#define MFMAQ(MH, NH)                                                          \
  _Pragma("unroll") for (int mi = 0; mi < 4; ++mi)                             \
    _Pragma("unroll") for (int ni = 0; ni < 2; ++ni)                           \
      _Pragma("unroll") for (int kk = 0; kk < 2; ++kk)                         \
        acc[(MH) * 4 + mi][(NH) * 2 + ni] =                                    \
            __builtin_amdgcn_mfma_f32_16x16x32_bf16(                           \
                a[mi][kk], b[(NH) * 2 + ni][kk],                               \
                acc[(MH) * 4 + mi][(NH) * 2 + ni], 0, 0, 0);

#define TILE(P, KC, MODE)                                                      \
  {                                                                            \
    const unsigned short* Ar = lds + wm * 16384 + (P) * 8192;                  \
    const unsigned short* Br =                                                 \
        lds + 32768 + (wn >> 1) * 16384 + (P) * 8192 + (wn & 1) * 4096;        \
    _Pragma("unroll") for (int mf = 0; mf < 4; ++mf) {                         \
      a[mf][0] = *reinterpret_cast<const bf16x8*>(Ar + mf * 1024 + ao0);       \
      a[mf][1] = *reinterpret_cast<const bf16x8*>(Ar + mf * 1024 + ao1);       \
    }                                                                          \
    _Pragma("unroll") for (int nf = 0; nf < 2; ++nf) {                         \
      b[nf][0] = *reinterpret_cast<const bf16x8*>(Br + nf * 1024 + ao0);       \
      b[nf][1] = *reinterpret_cast<const bf16x8*>(Br + nf * 1024 + ao1);       \
    }                                                                          \
    __builtin_amdgcn_s_setprio(1);                                             \
    MFMAQ(0, 0);                                                               \
    __builtin_amdgcn_s_setprio(0);                                             \
    _Pragma("unroll") for (int nf = 2; nf < 4; ++nf) {                         \
      b[nf][0] = *reinterpret_cast<const bf16x8*>(Br + nf * 1024 + ao0);       \
      b[nf][1] = *reinterpret_cast<const bf16x8*>(Br + nf * 1024 + ao1);       \
    }                                                                          \
    __builtin_amdgcn_s_setprio(1);                                             \
    MFMAQ(0, 1);                                                               \
    __builtin_amdgcn_s_setprio(0);                                             \
    asm volatile("s_waitcnt lgkmcnt(0)" ::: "memory");                         \
    asm volatile("s_barrier" ::: "memory"); /* B[.][P] fully read */           \
    if ((MODE) == 0) {                                                         \
      STG2(Bg, lds + 32768 + (P) * 8192, 0, KC);                               \
      STG2(Bg, lds + 49152 + (P) * 8192, 1, KC);                               \
    }                                                                          \
    _Pragma("unroll") for (int mf = 0; mf < 4; ++mf) {                         \
      a[mf][0] = *reinterpret_cast<const bf16x8*>(Ar + (4 + mf) * 1024 + ao0); \
      a[mf][1] = *reinterpret_cast<const bf16x8*>(Ar + (4 + mf) * 1024 + ao1); \
    }                                                                          \
    __builtin_amdgcn_s_setprio(1);                                             \
    MFMAQ(1, 0);                                                               \
    __builtin_amdgcn_s_setprio(0);                                             \
    asm volatile("s_waitcnt lgkmcnt(0)" ::: "memory");                         \
    asm volatile("s_barrier" ::: "memory"); /* A[.][P] fully read */           \
    if ((MODE) == 0) {                                                         \
      STG2(Ag, lds + (P) * 8192, 0, KC);                                       \
      STG2(Ag, lds + 16384 + (P) * 8192, 1, KC);                               \
    }                                                                          \
    __builtin_amdgcn_s_setprio(1);                                             \
    MFMAQ(1, 1);                                                               \
    __builtin_amdgcn_s_setprio(0);                                             \
    if ((MODE) == 0) asm volatile("s_waitcnt vmcnt(8)" ::: "memory");          \
    if ((MODE) == 1) asm volatile("s_waitcnt vmcnt(0)" ::: "memory");          \
    asm volatile("s_barrier" ::: "memory"); /* next tile's data landed */      \
  }

template <typename OUT_T>
__global__ __launch_bounds__(512, 2) void gemm256(const unsigned short* __restrict__ A,
                                                  const unsigned short* __restrict__ B,
                                                  OUT_T* __restrict__ C,
                                                  long Astride_z, long Cstride_z, int N) {
  __shared__ unsigned short lds[65536];   // 128 KiB
  const int tid = threadIdx.x;
  const int bn = blockIdx.x, bm = blockIdx.y, bz = blockIdx.z;
  const unsigned short* Ag = A + (long)bz * Astride_z + (long)bm * 256 * 4096;
  const unsigned short* Bg = B + (long)bn * 256 * 4096;

  const int w = tid >> 6, lane = tid & 63;
  const int wm = w >> 2, wn = w & 3;
  const int fr = lane & 15, fg = lane >> 4;
  const int ao0 = fr * 64 + ((fg ^ (fr & 7)) * 8);
  const int ao1 = fr * 64 + (((4 + fg) ^ (fr & 7)) * 8);
  const int srow = tid >> 3;
  const int sslot = (tid & 7) ^ (srow & 7);

  f32x4 acc[8][4] = {};
  bf16x8 a[4][2], b[4][2];

  STG2(Ag, lds + 0, 0, 0);     STG2(Ag, lds + 16384, 1, 0);
  STG2(Bg, lds + 32768, 0, 0); STG2(Bg, lds + 49152, 1, 0);
  STG2(Ag, lds + 8192, 0, 64);  STG2(Ag, lds + 24576, 1, 64);
  STG2(Bg, lds + 40960, 0, 64); STG2(Bg, lds + 57344, 1, 64);
  asm volatile("s_waitcnt vmcnt(8)" ::: "memory");
  asm volatile("s_barrier" ::: "memory");

  for (int ti = 0; ti < 31; ++ti) {        // tiles 0..61
    TILE(0, (2 * ti + 2) * 64, 0);
    TILE(1, (2 * ti + 3) * 64, 0);
  }
  TILE(0, 0, 1);
  TILE(1, 0, 2);

  OUT_T* Cb = C + (long)bz * Cstride_z + ((long)bm * 256) * N + bn * 256;
#pragma unroll
  for (int mf = 0; mf < 8; ++mf)
#pragma unroll
    for (int nf = 0; nf < 4; ++nf)
#pragma unroll
      for (int rr = 0; rr < 4; ++rr) {
        int row = wm * 128 + mf * 16 + fg * 4 + rr;
        int col = wn * 64 + nf * 16 + fr;
        storeC(Cb + (long)row * N + col, acc[mf][nf][rr]);
      }
}

// ---- flash attention (verified R11: R7 dbuf structure + T5 setprio) ----
// QBLK=64, kv tiles of 64 keys, K+V double-buffered via gload_lds.
// Per tile: STAGE(next, parity^1) | compute(current) | vmcnt0+lgkm0+barrier.
// K [key][16 slots] slot^(key&15); vT [feat][8 slots] slot^(feat&7).
// Per-lane defer-max, deferred l-reduce, exp2-domain softmax.
#define AT_STAGE(P, kv)                                                        \
  _Pragma("unroll") for (int i = 0; i < 4; i++) {                              \
    int c = tid + 256 * i;                                                     \
    int key = c >> 4, s0 = c & 15;                                             \
    int Lg = s0 ^ (key & 15);                                                  \
    load_lds16(kbase + (long)((kv) + key) * 4096 + Lg * 8, &Ks[P][c * 8]);     \
  }                                                                            \
  _Pragma("unroll") for (int i = 0; i < 4; i++) {                              \
    int c = tid + 256 * i;                                                     \
    int f0 = c >> 3, s0 = c & 7;                                               \
    int Lg = s0 ^ (f0 & 7);                                                    \
    load_lds16(vbase + (long)f0 * 8192 + (kv) + Lg * 8, &Vl[P][c * 8]);        \
  }

__global__ __launch_bounds__(256) void attn_fwd(const unsigned short* __restrict__ qb,
                                                const unsigned short* __restrict__ kb,
                                                const unsigned short* __restrict__ vT,
                                                unsigned short* __restrict__ ob) {
  __shared__ unsigned short Ks[2][64 * 128];   // 16KB x2
  __shared__ unsigned short Vl[2][128 * 64];   // 16KB x2
  __shared__ unsigned short Ps[4][16 * 72];    // 9KB

  const int qt = blockIdx.x, h = blockIdx.y, b = blockIdx.z;
  const int tid = threadIdx.x, w = tid >> 6, lane = tid & 63;
  const int fr = lane & 15, fg = lane >> 4;

  const unsigned short* kbase = kb + (long)b * 4096 * 4096 + h * 128;
  const unsigned short* vbase = vT + (long)h * 128 * 8192 + (long)b * 4096;

  // Q fragments: row = fr, k = fg*8 + c*32
  bf16x8 qf[4];
  {
    const unsigned short* qptr =
        qb + ((long)b * 1024 + qt * 64 + w * 16 + fr) * 4096 + h * 128 + fg * 8;
#pragma unroll
    for (int c = 0; c < 4; c++) qf[c] = *reinterpret_cast<const bf16x8*>(qptr + c * 32);
  }

  f32x4 outa[8] = {};
  float m_run[4], l_run[4];
#pragma unroll
  for (int r = 0; r < 4; r++) { m_run[r] = -1e30f; l_run[r] = 0.0f; }

  // prologue: stage tile 0 into parity 0
  AT_STAGE(0, 0);
  asm volatile("s_waitcnt vmcnt(0)" ::: "memory");
  asm volatile("s_barrier" ::: "memory");

  for (int t = 0; t < 64; ++t) {
    const int cur = t & 1;
    // issue next tile's staging early (writes other parity; hides HBM latency)
    if (t < 63) { AT_STAGE(cur ^ 1, (t + 1) * 64); }

    // S = Q K^T : 4 key-subtiles of 16
    f32x4 sacc[4];
    __builtin_amdgcn_s_setprio(1);
#pragma unroll
    for (int ks = 0; ks < 4; ks++) {
      f32x4 aq = {0.f, 0.f, 0.f, 0.f};
#pragma unroll
      for (int cc = 0; cc < 4; cc++) {
        bf16x8 kf = *reinterpret_cast<const bf16x8*>(
            &Ks[cur][(ks * 16 + fr) * 128 + (((cc * 4 + fg) ^ fr) & 15) * 8]);
        aq = __builtin_amdgcn_mfma_f32_16x16x32_bf16(qf[cc], kf, aq, 0, 0, 0);
      }
      sacc[ks] = aq;
    }
    __builtin_amdgcn_s_setprio(0);

    // per-lane defer-max (cross-lane reduce only when bound triggers)
    float mxl[4];
    int need = 0;
#pragma unroll
    for (int r = 0; r < 4; r++) {
      mxl[r] = fmaxf(fmaxf(sacc[0][r], sacc[1][r]), fmaxf(sacc[2][r], sacc[3][r]));
      need |= (mxl[r] > m_run[r] + 11.5f) ? 1 : 0;
    }
    if (__any(need)) {   // rare: full row max reduce + rescale
#pragma unroll
      for (int r = 0; r < 4; r++) {
        float mx = mxl[r];
        mx = fmaxf(mx, __shfl_xor(mx, 1));
        mx = fmaxf(mx, __shfl_xor(mx, 2));
        mx = fmaxf(mx, __shfl_xor(mx, 4));
        mx = fmaxf(mx, __shfl_xor(mx, 8));
        float mnew = fmaxf(m_run[r], mx);
        float ef = exp2f(m_run[r] - mnew);
        l_run[r] *= ef;
        m_run[r] = mnew;
#pragma unroll
        for (int ds = 0; ds < 8; ds++) outa[ds][r] *= ef;
      }
    }
#pragma unroll
    for (int r = 0; r < 4; r++) {
      float sum = 0.f;
#pragma unroll
      for (int ks = 0; ks < 4; ks++) {
        float pv = exp2f(sacc[ks][r] - m_run[r]);   // <= 2^11.5
        Ps[w][(fg * 4 + r) * 72 + ks * 16 + fr] = f32_to_bf16_bits(pv);
        sum += pv;
      }
      l_run[r] += sum;   // per-lane partial; cross-lane reduce at end
    }

    // O += P V
    __builtin_amdgcn_s_setprio(1);
#pragma unroll
    for (int c2 = 0; c2 < 2; c2++) {
      bf16x8 pf = *reinterpret_cast<const bf16x8*>(&Ps[w][fr * 72 + c2 * 32 + fg * 8]);
#pragma unroll
      for (int ds = 0; ds < 8; ds++) {
        int feat = ds * 16 + fr;
        int pch = ((c2 * 4 + fg) ^ (feat & 7)) & 7;
        bf16x8 vf = *reinterpret_cast<const bf16x8*>(&Vl[cur][feat * 64 + pch * 8]);
        outa[ds] = __builtin_amdgcn_mfma_f32_16x16x32_bf16(pf, vf, outa[ds], 0, 0, 0);
      }
    }
    __builtin_amdgcn_s_setprio(0);

    if (t < 63) {
      asm volatile("s_waitcnt vmcnt(0) lgkmcnt(0)" ::: "memory");
      asm volatile("s_barrier" ::: "memory");
    }
  }

  // final cross-lane l reduce (16 fr lanes), normalize, store
#pragma unroll
  for (int r = 0; r < 4; r++) {
    float l = l_run[r];
    l += __shfl_xor(l, 1);
    l += __shfl_xor(l, 2);
    l += __shfl_xor(l, 4);
    l += __shfl_xor(l, 8);
    float inv = 1.0f / l;
    unsigned short* op =
        ob + ((long)b * 1024 + qt * 64 + w * 16 + fg * 4 + r) * 4096 + h * 128;
#pragma unroll
    for (int ds = 0; ds < 8; ds++) op[ds * 16 + fr] = f32_to_bf16_bits(outa[ds][r] * inv);
  }
}

// ---------------------------------------------------------------------------
extern "C" void kernel_launch(void* const* d_in, const int* in_sizes, int n_in,
                              void* d_out, int out_size, void* d_ws, size_t ws_size,
                              hipStream_t stream) {
  const float* hs = (const float*)d_in[0];
  const float* wq = (const float*)d_in[1];
  const float* wk = (const float*)d_in[2];
  const float* wv = (const float*)d_in[3];
  const float* wo = (const float*)d_in[4];
  float* out = (float*)d_out;

  const long hsN = 2L * 4096 * 4096;
  const long wN  = 4096L * 4096;

  unsigned short* hs_b = (unsigned short*)d_ws;
  unsigned short* wq_b = hs_b + hsN;
  unsigned short* wk_b = wq_b + wN;
  unsigned short* wv_b = wk_b + wN;
  unsigned short* wo_b = wv_b + wN;
  unsigned short* q_b  = wo_b + wN;             // 2048 x 4096
  unsigned short* k_b  = q_b + 2048L * 4096;    // 8192 x 4096 ([tok][feat])
  unsigned short* vT_b = k_b + 8192L * 4096;    // 4096 x 8192 ([feat][tok])
  unsigned short* at_b = vT_b + 8192L * 4096;   // 2048 x 4096
  float* cos_t = (float*)(at_b + 2048L * 4096);
  float* sin_t = cos_t + 4096 * 64;

  cast_f32_bf16_batched<<<dim3(8192), dim3(256), 0, stream>>>(
      hs, wq, wk, wv, wo, hs_b);

  rope_tables<<<dim3(1024), dim3(256), 0, stream>>>(cos_t, sin_t);

  // Q[tok][feat] — 128^2 kernel
  gemm_bt<unsigned short><<<dim3(32, 8, 2), dim3(256), 0, stream>>>(
      hs_b, wq_b, q_b, 4096L * 4096, 1024L * 4096, 4096);
  // K[tok][feat] — 256^2 pipelined
  gemm256<unsigned short><<<dim3(16, 16, 2), dim3(512), 0, stream>>>(
      hs_b, wk_b, k_b, 4096L * 4096, 4096L * 4096, 4096);
  // vT[feat][tok] = Wv * hs^T — 256^2 pipelined
  gemm256<unsigned short><<<dim3(32, 16, 1), dim3(512), 0, stream>>>(
      wv_b, hs_b, vT_b, 0L, 0L, 8192);

  // merged RoPE (Q pre-scaled with scale*log2e for exp2-domain softmax)
  const float qgain = 0.08838834764831845f * 1.4426950408889634f;
  rope_apply_qk<<<dim3(10240), dim3(256), 0, stream>>>(
      q_b, k_b, (const float4*)cos_t, (const float4*)sin_t, qgain);

  attn_fwd<<<dim3(16, 32, 2), dim3(256), 0, stream>>>(q_b, k_b, vT_b, at_b);

  gemm_bt<float><<<dim3(32, 16, 1), dim3(256), 0, stream>>>(
      at_b, wo_b, out, 0L, 0L, 4096);
}